// Round 7
// baseline (519.388 us; speedup 1.0000x reference)
//
#include <hip/hip_runtime.h>
#include <stdint.h>

// softmax((x@q)@(x@k)) @ (x@v), N=2048, fp32 in/out.
// R12: gemm3 -> 256x256 tile, 8 waves at wave-tile 64x128 (+33% MFMA:LDS-read
// ratio vs R8's 64x64 -- the m201 intensity mechanism). BK=32, 2-buf 128KB
// LDS, grid (8,8,2)=128 blocks (z=2 keeps 2-partial consumers; half-GPU but
// ~2x per-CU throughput projected). Per step: 3 clusters of 32 MFMA with the
// R8 phase discipline; ALL 8 glds issued in phase 1 so the end-of-step
// VMCNT(0) (2-buf hazard) has ~3 MFMA clusters of latency cover.
// gemm1 + all elementwise kernels: R8-exact (best-known 390.8us config).
// Numerics unchanged (absmax 1.0 verified): fp16 2-term split, unscaled
// residual, 3 products (a0b0 + a1b0 + a0b1) into one acc; K-split z=0/1 ->
// W1/W2 plain stores; consumers add.

#define TN 2048

typedef float f32x4 __attribute__((ext_vector_type(4)));
typedef _Float16 f16;
typedef f16 f16x8 __attribute__((ext_vector_type(8)));
typedef f16 f16x4 __attribute__((ext_vector_type(4)));

#define MFMA16(a, b, c) __builtin_amdgcn_mfma_f32_16x16x32_f16(a, b, c, 0, 0, 0)
#define SBAR() asm volatile("s_barrier" ::: "memory")
#define VMCNT(n) asm volatile("s_waitcnt vmcnt(" #n ")" ::: "memory")

// async global->LDS, 16B/lane. lds base wave-uniform; HW adds lane*16.
__device__ __forceinline__ void glds16(const f16* g, f16* l) {
    __builtin_amdgcn_global_load_lds(
        (const __attribute__((address_space(1))) unsigned int*)g,
        (__attribute__((address_space(3))) unsigned int*)l, 16, 0, 0);
}

// ---------------- split kernels: a ~= t0 + t1 (residual UNSCALED) ----------------
__global__ void split2_kernel(const float* __restrict__ in,
                              f16* __restrict__ t0, f16* __restrict__ t1) {
    int i = (blockIdx.x * 256 + threadIdx.x) * 4;
    f32x4 f = *(const f32x4*)(in + i);
    f16x4 o0, o1;
#pragma unroll
    for (int e = 0; e < 4; ++e) {
        float a = f[e];
        f16 h0 = (f16)a;
        o0[e] = h0; o1[e] = (f16)(a - (float)h0);
    }
    *(f16x4*)(t0 + i) = o0; *(f16x4*)(t1 + i) = o1;
}

__global__ void split2_add_kernel(const float* __restrict__ inA,
                                  const float* __restrict__ inB,
                                  f16* __restrict__ t0, f16* __restrict__ t1) {
    int i = (blockIdx.x * 256 + threadIdx.x) * 4;
    f32x4 fa = *(const f32x4*)(inA + i);
    f32x4 fb = *(const f32x4*)(inB + i);
    f16x4 o0, o1;
#pragma unroll
    for (int e = 0; e < 4; ++e) {
        float a = fa[e] + fb[e];
        f16 h0 = (f16)a;
        o0[e] = h0; o1[e] = (f16)(a - (float)h0);
    }
    *(f16x4*)(t0 + i) = o0; *(f16x4*)(t1 + i) = o1;
}

__global__ void split2t_kernel(const float* __restrict__ in,
                               f16* __restrict__ t0, f16* __restrict__ t1) {
    __shared__ f16 s0[64][68], s1[64][68];
    int bc = blockIdx.x * 64, br = blockIdx.y * 64;
    int tx = threadIdx.x & 15, ty = threadIdx.x >> 4;
#pragma unroll
    for (int rr = 0; rr < 64; rr += 16) {
        int r = rr + ty;
        f32x4 f = *(const f32x4*)(in + (size_t)(br + r) * TN + bc + tx * 4);
#pragma unroll
        for (int e = 0; e < 4; ++e) {
            float a = f[e];
            f16 h0 = (f16)a;
            s0[tx * 4 + e][r] = h0; s1[tx * 4 + e][r] = (f16)(a - (float)h0);
        }
    }
    __syncthreads();
#pragma unroll
    for (int rr = 0; rr < 64; rr += 16) {
        int c = rr + ty;
        f16x4 o0, o1;
#pragma unroll
        for (int e = 0; e < 4; ++e) { o0[e] = s0[c][tx*4+e]; o1[e] = s1[c][tx*4+e]; }
        size_t off = (size_t)(bc + c) * TN + br + tx * 4;
        *(f16x4*)(t0 + off) = o0; *(f16x4*)(t1 + off) = o1;
    }
}

__global__ void split2t_add_kernel(const float* __restrict__ inA,
                                   const float* __restrict__ inB,
                                   f16* __restrict__ t0, f16* __restrict__ t1) {
    __shared__ f16 s0[64][68], s1[64][68];
    int bc = blockIdx.x * 64, br = blockIdx.y * 64;
    int tx = threadIdx.x & 15, ty = threadIdx.x >> 4;
#pragma unroll
    for (int rr = 0; rr < 64; rr += 16) {
        int r = rr + ty;
        size_t off = (size_t)(br + r) * TN + bc + tx * 4;
        f32x4 fa = *(const f32x4*)(inA + off);
        f32x4 fb = *(const f32x4*)(inB + off);
#pragma unroll
        for (int e = 0; e < 4; ++e) {
            float a = fa[e] + fb[e];
            f16 h0 = (f16)a;
            s0[tx * 4 + e][r] = h0; s1[tx * 4 + e][r] = (f16)(a - (float)h0);
        }
    }
    __syncthreads();
#pragma unroll
    for (int rr = 0; rr < 64; rr += 16) {
        int c = rr + ty;
        f16x4 o0, o1;
#pragma unroll
        for (int e = 0; e < 4; ++e) { o0[e] = s0[c][tx*4+e]; o1[e] = s1[c][tx*4+e]; }
        size_t off = (size_t)(bc + c) * TN + br + tx * 4;
        *(f16x4*)(t0 + off) = o0; *(f16x4*)(t1 + off) = o1;
    }
}

__global__ void cast1t_kernel(const float* __restrict__ in, f16* __restrict__ t0) {
    __shared__ f16 s0[64][68];
    int bc = blockIdx.x * 64, br = blockIdx.y * 64;
    int tx = threadIdx.x & 15, ty = threadIdx.x >> 4;
#pragma unroll
    for (int rr = 0; rr < 64; rr += 16) {
        int r = rr + ty;
        f32x4 f = *(const f32x4*)(in + (size_t)(br + r) * TN + bc + tx * 4);
#pragma unroll
        for (int e = 0; e < 4; ++e) s0[tx * 4 + e][r] = (f16)f[e];
    }
    __syncthreads();
#pragma unroll
    for (int rr = 0; rr < 64; rr += 16) {
        int c = rr + ty;
        f16x4 o0;
#pragma unroll
        for (int e = 0; e < 4; ++e) o0[e] = s0[c][tx*4+e];
        *(f16x4*)(t0 + (size_t)(bc + c) * TN + br + tx * 4) = o0;
    }
}

__global__ void cast1t_add_kernel(const float* __restrict__ inA,
                                  const float* __restrict__ inB,
                                  f16* __restrict__ t0) {
    __shared__ f16 s0[64][68];
    int bc = blockIdx.x * 64, br = blockIdx.y * 64;
    int tx = threadIdx.x & 15, ty = threadIdx.x >> 4;
#pragma unroll
    for (int rr = 0; rr < 64; rr += 16) {
        int r = rr + ty;
        size_t off = (size_t)(br + r) * TN + bc + tx * 4;
        f32x4 fa = *(const f32x4*)(inA + off);
        f32x4 fb = *(const f32x4*)(inB + off);
#pragma unroll
        for (int e = 0; e < 4; ++e) s0[tx * 4 + e][r] = (f16)(fa[e] + fb[e]);
    }
    __syncthreads();
#pragma unroll
    for (int rr = 0; rr < 64; rr += 16) {
        int c = rr + ty;
        f16x4 o0;
#pragma unroll
        for (int e = 0; e < 4; ++e) o0[e] = s0[c][tx*4+e];
        *(f16x4*)(t0 + (size_t)(bc + c) * TN + br + tx * 4) = o0;
    }
}

__global__ void final_add_kernel(const float* __restrict__ inA,
                                 const float* __restrict__ inB,
                                 float* __restrict__ out) {
    int i = (blockIdx.x * 256 + threadIdx.x) * 4;
    f32x4 fa = *(const f32x4*)(inA + i);
    f32x4 fb = *(const f32x4*)(inB + i);
    f32x4 o;
#pragma unroll
    for (int e = 0; e < 4; ++e) o[e] = fa[e] + fb[e];
    *(f32x4*)(out + i) = o;
}

// ---------------- 3-product split GEMM, 256x256 tile, 8 waves @ 64x128, 2-buf ----------------
// Segs (1KB = 16 rows x 32 K): 0-15 a0, 16-31 a1, 32-47 b0, 48-63 b1.
// Per step:
// P1: [read a1f(4)][glds ALL 8 -> nxt][SBAR][MFMA a0*b0 (32)][SBAR]
// P2: [read b1f(8)][SBAR][MFMA a1*b0 (32)][SBAR]
// P3: [MFMA a0*b1 (32)][VMCNT(0)][SBAR][read a0f(4), b0f(8) from nxt]
__global__ __launch_bounds__(512, 2) void gemm3_f16(
    const f16* __restrict__ a0p, const f16* __restrict__ a1p,
    const f16* __restrict__ b0p, const f16* __restrict__ b1p,
    float* __restrict__ C0, float* __restrict__ C1) {
    __shared__ f16 lds[2][64 * 512];  // 128 KB
    const int tid = threadIdx.x;
    const int wave = tid >> 6, lane = tid & 63;
    const int wrow = wave >> 1, wcol = wave & 1;   // 4x2 waves, tile 64x128 each
    const int quad = lane >> 4, l16 = lane & 15;
    const int bm = blockIdx.y * 256, bn = blockIdx.x * 256;
    const int kbase = blockIdx.z * 1024;
    float* __restrict__ C = blockIdx.z ? C1 : C0;

    const int ws = wave * 8;
    const f16* sp[8];
#pragma unroll
    for (int t = 0; t < 8; ++t) {
        int s = ws + t;
        const f16* base; int gr;
        if (s < 16)      { base = a0p; gr = bm + s * 16 + l16; }
        else if (s < 32) { base = a1p; gr = bm + (s - 16) * 16 + l16; }
        else if (s < 48) { base = b0p; gr = bn + (s - 32) * 16 + l16; }
        else             { base = b1p; gr = bn + (s - 48) * 16 + l16; }
        sp[t] = base + (size_t)gr * TN + kbase + quad * 8;
    }
    const int rof = lane * 8;
    const int sa0 = wrow * 4,      sa1 = 16 + wrow * 4;
    const int sb0 = 32 + wcol * 8, sb1 = 48 + wcol * 8;

    f32x4 acc[4][8];
#pragma unroll
    for (int i = 0; i < 4; ++i)
#pragma unroll
        for (int j = 0; j < 8; ++j) acc[i][j] = (f32x4){0.f, 0.f, 0.f, 0.f};

    // prologue: step0 -> buf0
#pragma unroll
    for (int t = 0; t < 8; ++t) { glds16(sp[t], &lds[0][(ws + t) * 512]); sp[t] += 32; }
    f16* cur = &lds[0][0]; f16* nxt = &lds[1][0];
    VMCNT(0); SBAR();

    f16x8 a0f[4], a1f[4], b0f[8], b1f[8];
#pragma unroll
    for (int i = 0; i < 4; ++i) a0f[i] = *(const f16x8*)(cur + (sa0 + i) * 512 + rof);
#pragma unroll
    for (int j = 0; j < 8; ++j) b0f[j] = *(const f16x8*)(cur + (sb0 + j) * 512 + rof);

    for (int step = 0; step < 32; ++step) {
        // ---- P1 ----
#pragma unroll
        for (int i = 0; i < 4; ++i) a1f[i] = *(const f16x8*)(cur + (sa1 + i) * 512 + rof);
        if (step < 31) {
#pragma unroll
            for (int t = 0; t < 8; ++t) { glds16(sp[t], nxt + (ws + t) * 512); sp[t] += 32; }
        }
        SBAR();
        __builtin_amdgcn_s_setprio(1);
#pragma unroll
        for (int i = 0; i < 4; ++i)
#pragma unroll
            for (int j = 0; j < 8; ++j) acc[i][j] = MFMA16(a0f[i], b0f[j], acc[i][j]);
        __builtin_amdgcn_s_setprio(0);
        SBAR();
        // ---- P2 ----
#pragma unroll
        for (int j = 0; j < 8; ++j) b1f[j] = *(const f16x8*)(cur + (sb1 + j) * 512 + rof);
        SBAR();
        __builtin_amdgcn_s_setprio(1);
#pragma unroll
        for (int i = 0; i < 4; ++i)
#pragma unroll
            for (int j = 0; j < 8; ++j) acc[i][j] = MFMA16(a1f[i], b0f[j], acc[i][j]);
        __builtin_amdgcn_s_setprio(0);
        SBAR();
        // ---- P3 ----
        __builtin_amdgcn_s_setprio(1);
#pragma unroll
        for (int i = 0; i < 4; ++i)
#pragma unroll
            for (int j = 0; j < 8; ++j) acc[i][j] = MFMA16(a0f[i], b1f[j], acc[i][j]);
        __builtin_amdgcn_s_setprio(0);
        if (step < 31) {
            VMCNT(0);
            SBAR();
#pragma unroll
            for (int i = 0; i < 4; ++i) a0f[i] = *(const f16x8*)(nxt + (sa0 + i) * 512 + rof);
#pragma unroll
            for (int j = 0; j < 8; ++j) b0f[j] = *(const f16x8*)(nxt + (sb0 + j) * 512 + rof);
        }
        f16* tmp = cur; cur = nxt; nxt = tmp;
    }
#pragma unroll
    for (int i = 0; i < 4; ++i)
#pragma unroll
        for (int j = 0; j < 8; ++j) {
            int row = bm + wrow * 64 + i * 16 + quad * 4;
            int col = bn + wcol * 128 + j * 16 + l16;
            float* p = C + (size_t)row * TN + col;
#pragma unroll
            for (int r = 0; r < 4; ++r) p[(size_t)r * TN] = acc[i][j][r];
        }
}

// ---------------- single-product GEMM, 128x128, 4 waves, 3-buf pipeline (R8) ----------------
__global__ __launch_bounds__(256, 2) void gemm1_f16(
    const f16* __restrict__ A, const f16* __restrict__ Bt,
    float* __restrict__ C0, float* __restrict__ C1) {
    __shared__ f16 lds[3][16 * 512];  // 48 KB
    const int tid = threadIdx.x;
    const int wave = tid >> 6, lane = tid & 63;
    const int wr = (wave >> 1) * 64, wc = (wave & 1) * 64;
    const int quad = lane >> 4, l16 = lane & 15;
    const int bm = blockIdx.y * 128, bn = blockIdx.x * 128;
    const int kbase = blockIdx.z * 1024;
    float* __restrict__ C = blockIdx.z ? C1 : C0;

    const int ws = wave * 4;
    const f16* sp[4];
#pragma unroll
    for (int t = 0; t < 4; ++t) {
        int s = ws + t;
        const f16* base; int gr;
        if (s < 8) { base = A;  gr = bm + s * 16 + l16; }
        else       { base = Bt; gr = bn + (s - 8) * 16 + l16; }
        sp[t] = base + (size_t)gr * TN + kbase + quad * 8;
    }
    const int rof = lane * 8;
    const int sa = (wr >> 4), sb = 8 + (wc >> 4);

    f32x4 acc[4][4];
#pragma unroll
    for (int i = 0; i < 4; ++i)
#pragma unroll
        for (int j = 0; j < 4; ++j) acc[i][j] = (f32x4){0.f, 0.f, 0.f, 0.f};

#pragma unroll
    for (int t = 0; t < 4; ++t) { glds16(sp[t], &lds[0][(ws + t) * 512]); sp[t] += 32; }
#pragma unroll
    for (int t = 0; t < 4; ++t) { glds16(sp[t], &lds[1][(ws + t) * 512]); sp[t] += 32; }
    f16* cur = &lds[0][0]; f16* nxt = &lds[1][0]; f16* pre = &lds[2][0];
    VMCNT(4); SBAR();

    f16x8 af[4], bf[4];
#pragma unroll
    for (int i = 0; i < 4; ++i) af[i] = *(const f16x8*)(cur + (sa + i) * 512 + rof);
#pragma unroll
    for (int j = 0; j < 4; ++j) bf[j] = *(const f16x8*)(cur + (sb + j) * 512 + rof);

    for (int step = 0; step < 32; ++step) {
        if (step < 30) {
#pragma unroll
            for (int t = 0; t < 4; ++t) { glds16(sp[t], pre + (ws + t) * 512); sp[t] += 32; }
        }
        SBAR();
        __builtin_amdgcn_s_setprio(1);
#pragma unroll
        for (int i = 0; i < 4; ++i)
#pragma unroll
            for (int j = 0; j < 4; ++j) acc[i][j] = MFMA16(af[i], bf[j], acc[i][j]);
        __builtin_amdgcn_s_setprio(0);
        if (step < 31) {
            if (step < 30) { VMCNT(4); } else { VMCNT(0); }
            SBAR();
#pragma unroll
            for (int i = 0; i < 4; ++i) af[i] = *(const f16x8*)(nxt + (sa + i) * 512 + rof);
#pragma unroll
            for (int j = 0; j < 4; ++j) bf[j] = *(const f16x8*)(nxt + (sb + j) * 512 + rof);
        }
        f16* tmp = cur; cur = nxt; nxt = pre; pre = tmp;
    }
#pragma unroll
    for (int i = 0; i < 4; ++i)
#pragma unroll
        for (int j = 0; j < 4; ++j) {
            int row = bm + wr + i * 16 + quad * 4;
            int col = bn + wc + j * 16 + l16;
            float* p = C + (size_t)row * TN + col;
#pragma unroll
            for (int r = 0; r < 4; ++r) p[(size_t)r * TN] = acc[i][j][r];
        }
}

// ---------------- softmax of (S0+S1), single-pass (fp32 in, fp16 P out) ----------------
__global__ void softmax_add_kernel(const float* __restrict__ S0,
                                   const float* __restrict__ S1,
                                   f16* __restrict__ P) {
    __shared__ float red[256];
    const int row = blockIdx.x, tid = threadIdx.x;
    const size_t base = (size_t)row * TN + tid * 8;
    f32x4 a0 = *(const f32x4*)(S0 + base);
    f32x4 a1 = *(const f32x4*)(S0 + base + 4);
    f32x4 b0 = *(const f32x4*)(S1 + base);
    f32x4 b1 = *(const f32x4*)(S1 + base + 4);
    float vals[8];
#pragma unroll
    for (int e = 0; e < 4; ++e) { vals[e] = a0[e] + b0[e]; vals[4 + e] = a1[e] + b1[e]; }
    float m = vals[0];
#pragma unroll
    for (int e = 1; e < 8; ++e) m = fmaxf(m, vals[e]);
    red[tid] = m; __syncthreads();
    for (int st = 128; st > 0; st >>= 1) { if (tid < st) red[tid] = fmaxf(red[tid], red[tid + st]); __syncthreads(); }
    m = red[0]; __syncthreads();
    float sum = 0.f;
#pragma unroll
    for (int e = 0; e < 8; ++e) { vals[e] = expf(vals[e] - m); sum += vals[e]; }
    red[tid] = sum; __syncthreads();
    for (int st = 128; st > 0; st >>= 1) { if (tid < st) red[tid] += red[tid + st]; __syncthreads(); }
    float inv = 1.f / red[0];
    f16x8 o;
#pragma unroll
    for (int e = 0; e < 8; ++e) o[e] = (f16)(vals[e] * inv);
    *(f16x8*)(P + base) = o;
}

extern "C" void kernel_launch(void* const* d_in, const int* in_sizes, int n_in,
                              void* d_out, int out_size, void* d_ws, size_t ws_size,
                              hipStream_t stream) {
    const float* x = (const float*)d_in[0];
    const float* q = (const float*)d_in[1];
    const float* k = (const float*)d_in[2];
    const float* v = (const float*)d_in[3];
    float* out = (float*)d_out;
    const size_t M = (size_t)TN * TN;

    float* W1 = (float*)d_ws;
    float* W2 = W1 + M;
    f16* pl = (f16*)(W2 + M);
    f16 *x0 = pl,         *x1 = pl + M;
    f16 *q0 = pl + 2 * M, *q1 = pl + 3 * M;
    f16 *k0 = pl + 4 * M, *k1 = pl + 5 * M;
    f16 *v0 = pl + 6 * M;
    f16 *a0 = q0, *a1 = q1;   // xq split reuses q planes
    f16 *b0 = k0, *b1 = k1;   // xk split reuses k planes
    f16 *p0 = x1, *c0 = x0;   // P reuses x1, C reuses x0

    dim3 bs(256), bs3(512);
    dim3 gelem(TN * TN / 4 / 256);
    dim3 gt(TN / 64, TN / 64);
    dim3 gg3(TN / 256, TN / 256, 2);   // 128 blocks (256^2 tiles), z=2
    dim3 gg1(TN / 128, TN / 128, 2);   // 512 blocks, 2/CU

    hipLaunchKernelGGL(split2_kernel,  gelem, bs, 0, stream, x, x0, x1);
    hipLaunchKernelGGL(cast1t_kernel,  gt,    bs, 0, stream, v, v0);
    hipLaunchKernelGGL(split2t_kernel, gt,    bs, 0, stream, q, q0, q1);
    hipLaunchKernelGGL(gemm3_f16, gg3, bs3, 0, stream, x0, x1, q0, q1, W1, W2);
    hipLaunchKernelGGL(split2_add_kernel, gelem, bs, 0, stream, W1, W2, a0, a1);
    hipLaunchKernelGGL(split2t_kernel, gt, bs, 0, stream, k, k0, k1);
    hipLaunchKernelGGL(gemm3_f16, gg3, bs3, 0, stream, x0, x1, k0, k1, W1, W2);
    hipLaunchKernelGGL(split2t_add_kernel, gt, bs, 0, stream, W1, W2, b0, b1);
    hipLaunchKernelGGL(gemm3_f16, gg3, bs3, 0, stream, a0, a1, b0, b1, W1, W2);
    hipLaunchKernelGGL(softmax_add_kernel, dim3(TN), bs, 0, stream, W1, W2, p0);
    hipLaunchKernelGGL(gemm1_f16, gg1, bs, 0, stream, x0, v0, W1, W2);
    hipLaunchKernelGGL(cast1t_add_kernel, gt, bs, 0, stream, W1, W2, c0);
    hipLaunchKernelGGL(gemm1_f16, gg1, bs, 0, stream, p0, c0, W1, W2);
    hipLaunchKernelGGL(final_add_kernel, gelem, bs, 0, stream, W1, W2, out);
}

// Round 8
// 391.327 us; speedup vs baseline: 1.3272x; 1.3272x over previous
//
#include <hip/hip_runtime.h>
#include <stdint.h>

// softmax((x@q)@(x@k)) @ (x@v), N=2048, fp32 in/out.
// R13: gemm3 = R9's verified one-barrier/step skeleton (128x256, 8 waves,
// 3-buf 144KB, glds 2 steps ahead, counted VMCNT(6)) + FORCED read/MFMA
// interleave via sched_group_barrier: b1f[i]/a1f[i] ds_reads pinned 1-per-
// 4-MFMA-quad inside clusters 1-2 (they're consumed one cluster later), so
// the LDS pipe runs during the MFMA window instead of serializing phase-wise
// (R12 post-mortem: wall = SUM of read+MFMA clusters, not max). a0f/b0f read
// at step top post-barrier. setprio(1) over the MFMA region. Correctness =
// R9's (SGB only constrains scheduling; lgkmcnt deps unchanged).
// gemm1 + elementwise + launcher: R8-exact (best-known 390.8us config).
// Numerics unchanged (absmax 1.0): fp16 2-term split, unscaled residual,
// 3 products into one acc; K-split z=0/1 -> W1/W2 plain stores; consumers add.

#define TN 2048

typedef float f32x4 __attribute__((ext_vector_type(4)));
typedef _Float16 f16;
typedef f16 f16x8 __attribute__((ext_vector_type(8)));
typedef f16 f16x4 __attribute__((ext_vector_type(4)));

#define MFMA16(a, b, c) __builtin_amdgcn_mfma_f32_16x16x32_f16(a, b, c, 0, 0, 0)
#define SBAR() asm volatile("s_barrier" ::: "memory")
#define VMCNT(n) asm volatile("s_waitcnt vmcnt(" #n ")" ::: "memory")
#define SGB(mask, n) __builtin_amdgcn_sched_group_barrier(mask, n, 0)

// async global->LDS, 16B/lane. lds base wave-uniform; HW adds lane*16.
__device__ __forceinline__ void glds16(const f16* g, f16* l) {
    __builtin_amdgcn_global_load_lds(
        (const __attribute__((address_space(1))) unsigned int*)g,
        (__attribute__((address_space(3))) unsigned int*)l, 16, 0, 0);
}

// ---------------- split kernels: a ~= t0 + t1 (residual UNSCALED) ----------------
__global__ void split2_kernel(const float* __restrict__ in,
                              f16* __restrict__ t0, f16* __restrict__ t1) {
    int i = (blockIdx.x * 256 + threadIdx.x) * 4;
    f32x4 f = *(const f32x4*)(in + i);
    f16x4 o0, o1;
#pragma unroll
    for (int e = 0; e < 4; ++e) {
        float a = f[e];
        f16 h0 = (f16)a;
        o0[e] = h0; o1[e] = (f16)(a - (float)h0);
    }
    *(f16x4*)(t0 + i) = o0; *(f16x4*)(t1 + i) = o1;
}

__global__ void split2_add_kernel(const float* __restrict__ inA,
                                  const float* __restrict__ inB,
                                  f16* __restrict__ t0, f16* __restrict__ t1) {
    int i = (blockIdx.x * 256 + threadIdx.x) * 4;
    f32x4 fa = *(const f32x4*)(inA + i);
    f32x4 fb = *(const f32x4*)(inB + i);
    f16x4 o0, o1;
#pragma unroll
    for (int e = 0; e < 4; ++e) {
        float a = fa[e] + fb[e];
        f16 h0 = (f16)a;
        o0[e] = h0; o1[e] = (f16)(a - (float)h0);
    }
    *(f16x4*)(t0 + i) = o0; *(f16x4*)(t1 + i) = o1;
}

__global__ void split2t_kernel(const float* __restrict__ in,
                               f16* __restrict__ t0, f16* __restrict__ t1) {
    __shared__ f16 s0[64][68], s1[64][68];
    int bc = blockIdx.x * 64, br = blockIdx.y * 64;
    int tx = threadIdx.x & 15, ty = threadIdx.x >> 4;
#pragma unroll
    for (int rr = 0; rr < 64; rr += 16) {
        int r = rr + ty;
        f32x4 f = *(const f32x4*)(in + (size_t)(br + r) * TN + bc + tx * 4);
#pragma unroll
        for (int e = 0; e < 4; ++e) {
            float a = f[e];
            f16 h0 = (f16)a;
            s0[tx * 4 + e][r] = h0; s1[tx * 4 + e][r] = (f16)(a - (float)h0);
        }
    }
    __syncthreads();
#pragma unroll
    for (int rr = 0; rr < 64; rr += 16) {
        int c = rr + ty;
        f16x4 o0, o1;
#pragma unroll
        for (int e = 0; e < 4; ++e) { o0[e] = s0[c][tx*4+e]; o1[e] = s1[c][tx*4+e]; }
        size_t off = (size_t)(bc + c) * TN + br + tx * 4;
        *(f16x4*)(t0 + off) = o0; *(f16x4*)(t1 + off) = o1;
    }
}

__global__ void split2t_add_kernel(const float* __restrict__ inA,
                                   const float* __restrict__ inB,
                                   f16* __restrict__ t0, f16* __restrict__ t1) {
    __shared__ f16 s0[64][68], s1[64][68];
    int bc = blockIdx.x * 64, br = blockIdx.y * 64;
    int tx = threadIdx.x & 15, ty = threadIdx.x >> 4;
#pragma unroll
    for (int rr = 0; rr < 64; rr += 16) {
        int r = rr + ty;
        size_t off = (size_t)(br + r) * TN + bc + tx * 4;
        f32x4 fa = *(const f32x4*)(inA + off);
        f32x4 fb = *(const f32x4*)(inB + off);
#pragma unroll
        for (int e = 0; e < 4; ++e) {
            float a = fa[e] + fb[e];
            f16 h0 = (f16)a;
            s0[tx * 4 + e][r] = h0; s1[tx * 4 + e][r] = (f16)(a - (float)h0);
        }
    }
    __syncthreads();
#pragma unroll
    for (int rr = 0; rr < 64; rr += 16) {
        int c = rr + ty;
        f16x4 o0, o1;
#pragma unroll
        for (int e = 0; e < 4; ++e) { o0[e] = s0[c][tx*4+e]; o1[e] = s1[c][tx*4+e]; }
        size_t off = (size_t)(bc + c) * TN + br + tx * 4;
        *(f16x4*)(t0 + off) = o0; *(f16x4*)(t1 + off) = o1;
    }
}

__global__ void cast1t_kernel(const float* __restrict__ in, f16* __restrict__ t0) {
    __shared__ f16 s0[64][68];
    int bc = blockIdx.x * 64, br = blockIdx.y * 64;
    int tx = threadIdx.x & 15, ty = threadIdx.x >> 4;
#pragma unroll
    for (int rr = 0; rr < 64; rr += 16) {
        int r = rr + ty;
        f32x4 f = *(const f32x4*)(in + (size_t)(br + r) * TN + bc + tx * 4);
#pragma unroll
        for (int e = 0; e < 4; ++e) s0[tx * 4 + e][r] = (f16)f[e];
    }
    __syncthreads();
#pragma unroll
    for (int rr = 0; rr < 64; rr += 16) {
        int c = rr + ty;
        f16x4 o0;
#pragma unroll
        for (int e = 0; e < 4; ++e) o0[e] = s0[c][tx*4+e];
        *(f16x4*)(t0 + (size_t)(bc + c) * TN + br + tx * 4) = o0;
    }
}

__global__ void cast1t_add_kernel(const float* __restrict__ inA,
                                  const float* __restrict__ inB,
                                  f16* __restrict__ t0) {
    __shared__ f16 s0[64][68];
    int bc = blockIdx.x * 64, br = blockIdx.y * 64;
    int tx = threadIdx.x & 15, ty = threadIdx.x >> 4;
#pragma unroll
    for (int rr = 0; rr < 64; rr += 16) {
        int r = rr + ty;
        size_t off = (size_t)(br + r) * TN + bc + tx * 4;
        f32x4 fa = *(const f32x4*)(inA + off);
        f32x4 fb = *(const f32x4*)(inB + off);
#pragma unroll
        for (int e = 0; e < 4; ++e) s0[tx * 4 + e][r] = (f16)(fa[e] + fb[e]);
    }
    __syncthreads();
#pragma unroll
    for (int rr = 0; rr < 64; rr += 16) {
        int c = rr + ty;
        f16x4 o0;
#pragma unroll
        for (int e = 0; e < 4; ++e) o0[e] = s0[c][tx*4+e];
        *(f16x4*)(t0 + (size_t)(bc + c) * TN + br + tx * 4) = o0;
    }
}

__global__ void final_add_kernel(const float* __restrict__ inA,
                                 const float* __restrict__ inB,
                                 float* __restrict__ out) {
    int i = (blockIdx.x * 256 + threadIdx.x) * 4;
    f32x4 fa = *(const f32x4*)(inA + i);
    f32x4 fb = *(const f32x4*)(inB + i);
    f32x4 o;
#pragma unroll
    for (int e = 0; e < 4; ++e) o[e] = fa[e] + fb[e];
    *(f32x4*)(out + i) = o;
}

// ---------------- 3-product split GEMM, 128x256, 8 waves, 3-buf, interleaved ----------------
// Per step (ONE barrier): [read a0f,b0f(cur)][glds x6 -> pre]
// [cluster1 a0*b0, 1 b1f-read per quad][cluster2 a0*b1, 1 a1f-read per quad]
// [cluster3 a1*b0][VMCNT(6)][SBAR]
__global__ __launch_bounds__(512, 2) void gemm3_f16(
    const f16* __restrict__ a0p, const f16* __restrict__ a1p,
    const f16* __restrict__ b0p, const f16* __restrict__ b1p,
    float* __restrict__ C0, float* __restrict__ C1) {
    __shared__ f16 lds[3][48 * 512];  // 144 KB
    const int tid = threadIdx.x;
    const int wave = tid >> 6, lane = tid & 63;
    const int wrow = wave >> 2, wcol = wave & 3;
    const int quad = lane >> 4, l16 = lane & 15;
    const int bm = blockIdx.y * 128, bn = blockIdx.x * 256;
    const int kbase = blockIdx.z * 1024;
    float* __restrict__ C = blockIdx.z ? C1 : C0;

    const int ws = wave * 6;
    const f16* sp[6];
#pragma unroll
    for (int t = 0; t < 6; ++t) {
        int s = ws + t;
        const f16* base; int gr;
        if (s < 8)       { base = a0p; gr = bm + s * 16 + l16; }
        else if (s < 16) { base = a1p; gr = bm + (s - 8) * 16 + l16; }
        else if (s < 32) { base = b0p; gr = bn + (s - 16) * 16 + l16; }
        else             { base = b1p; gr = bn + (s - 32) * 16 + l16; }
        sp[t] = base + (size_t)gr * TN + kbase + quad * 8;
    }
    const int rof = lane * 8;
    const int sa0 = wrow * 4, sa1 = 8 + wrow * 4;
    const int sb0 = 16 + wcol * 4, sb1 = 32 + wcol * 4;

    f32x4 acc[4][4];
#pragma unroll
    for (int i = 0; i < 4; ++i)
#pragma unroll
        for (int j = 0; j < 4; ++j) acc[i][j] = (f32x4){0.f, 0.f, 0.f, 0.f};

    // prologue: batches for step0 -> buf0, step1 -> buf1
#pragma unroll
    for (int t = 0; t < 6; ++t) { glds16(sp[t], &lds[0][(ws + t) * 512]); sp[t] += 32; }
#pragma unroll
    for (int t = 0; t < 6; ++t) { glds16(sp[t], &lds[1][(ws + t) * 512]); sp[t] += 32; }
    f16* cur = &lds[0][0]; f16* nxt = &lds[1][0]; f16* pre = &lds[2][0];
    VMCNT(6); SBAR();

    f16x8 a0f[4], a1f[4], b0f[4], b1f[4];
    for (int step = 0; step < 32; ++step) {
        // cur valid for all waves (post-barrier)
#pragma unroll
        for (int i = 0; i < 4; ++i) a0f[i] = *(const f16x8*)(cur + (sa0 + i) * 512 + rof);
#pragma unroll
        for (int j = 0; j < 4; ++j) b0f[j] = *(const f16x8*)(cur + (sb0 + j) * 512 + rof);
        if (step < 30) {
#pragma unroll
            for (int t = 0; t < 6; ++t) { glds16(sp[t], pre + (ws + t) * 512); sp[t] += 32; }
        }
        __builtin_amdgcn_s_setprio(1);
        // cluster 1: a0*b0, interleave b1f reads (used in cluster 2)
#pragma unroll
        for (int i = 0; i < 4; ++i) {
            b1f[i] = *(const f16x8*)(cur + (sb1 + i) * 512 + rof);
#pragma unroll
            for (int j = 0; j < 4; ++j) acc[i][j] = MFMA16(a0f[i], b0f[j], acc[i][j]);
            SGB(0x100, 1); SGB(0x8, 4);
        }
        // cluster 2: a0*b1, interleave a1f reads (used in cluster 3)
#pragma unroll
        for (int i = 0; i < 4; ++i) {
            a1f[i] = *(const f16x8*)(cur + (sa1 + i) * 512 + rof);
#pragma unroll
            for (int j = 0; j < 4; ++j) acc[i][j] = MFMA16(a0f[i], b1f[j], acc[i][j]);
            SGB(0x100, 1); SGB(0x8, 4);
        }
        // cluster 3: a1*b0
#pragma unroll
        for (int i = 0; i < 4; ++i)
#pragma unroll
            for (int j = 0; j < 4; ++j) acc[i][j] = MFMA16(a1f[i], b0f[j], acc[i][j]);
        __builtin_amdgcn_s_setprio(0);
        if (step < 31) {
            if (step < 30) { VMCNT(6); } else { VMCNT(0); }
            SBAR();
        }
        f16* tmp = cur; cur = nxt; nxt = pre; pre = tmp;
    }
#pragma unroll
    for (int i = 0; i < 4; ++i)
#pragma unroll
        for (int j = 0; j < 4; ++j) {
            int row = bm + wrow * 64 + i * 16 + quad * 4;
            int col = bn + wcol * 64 + j * 16 + l16;
            float* p = C + (size_t)row * TN + col;
#pragma unroll
            for (int r = 0; r < 4; ++r) p[(size_t)r * TN] = acc[i][j][r];
        }
}

// ---------------- single-product GEMM, 128x128, 4 waves, 3-buf pipeline (R8) ----------------
__global__ __launch_bounds__(256, 2) void gemm1_f16(
    const f16* __restrict__ A, const f16* __restrict__ Bt,
    float* __restrict__ C0, float* __restrict__ C1) {
    __shared__ f16 lds[3][16 * 512];  // 48 KB
    const int tid = threadIdx.x;
    const int wave = tid >> 6, lane = tid & 63;
    const int wr = (wave >> 1) * 64, wc = (wave & 1) * 64;
    const int quad = lane >> 4, l16 = lane & 15;
    const int bm = blockIdx.y * 128, bn = blockIdx.x * 128;
    const int kbase = blockIdx.z * 1024;
    float* __restrict__ C = blockIdx.z ? C1 : C0;

    const int ws = wave * 4;
    const f16* sp[4];
#pragma unroll
    for (int t = 0; t < 4; ++t) {
        int s = ws + t;
        const f16* base; int gr;
        if (s < 8) { base = A;  gr = bm + s * 16 + l16; }
        else       { base = Bt; gr = bn + (s - 8) * 16 + l16; }
        sp[t] = base + (size_t)gr * TN + kbase + quad * 8;
    }
    const int rof = lane * 8;
    const int sa = (wr >> 4), sb = 8 + (wc >> 4);

    f32x4 acc[4][4];
#pragma unroll
    for (int i = 0; i < 4; ++i)
#pragma unroll
        for (int j = 0; j < 4; ++j) acc[i][j] = (f32x4){0.f, 0.f, 0.f, 0.f};

#pragma unroll
    for (int t = 0; t < 4; ++t) { glds16(sp[t], &lds[0][(ws + t) * 512]); sp[t] += 32; }
#pragma unroll
    for (int t = 0; t < 4; ++t) { glds16(sp[t], &lds[1][(ws + t) * 512]); sp[t] += 32; }
    f16* cur = &lds[0][0]; f16* nxt = &lds[1][0]; f16* pre = &lds[2][0];
    VMCNT(4); SBAR();

    f16x8 af[4], bf[4];
#pragma unroll
    for (int i = 0; i < 4; ++i) af[i] = *(const f16x8*)(cur + (sa + i) * 512 + rof);
#pragma unroll
    for (int j = 0; j < 4; ++j) bf[j] = *(const f16x8*)(cur + (sb + j) * 512 + rof);

    for (int step = 0; step < 32; ++step) {
        if (step < 30) {
#pragma unroll
            for (int t = 0; t < 4; ++t) { glds16(sp[t], pre + (ws + t) * 512); sp[t] += 32; }
        }
        SBAR();
        __builtin_amdgcn_s_setprio(1);
#pragma unroll
        for (int i = 0; i < 4; ++i)
#pragma unroll
            for (int j = 0; j < 4; ++j) acc[i][j] = MFMA16(af[i], bf[j], acc[i][j]);
        __builtin_amdgcn_s_setprio(0);
        if (step < 31) {
            if (step < 30) { VMCNT(4); } else { VMCNT(0); }
            SBAR();
#pragma unroll
            for (int i = 0; i < 4; ++i) af[i] = *(const f16x8*)(nxt + (sa + i) * 512 + rof);
#pragma unroll
            for (int j = 0; j < 4; ++j) bf[j] = *(const f16x8*)(nxt + (sb + j) * 512 + rof);
        }
        f16* tmp = cur; cur = nxt; nxt = pre; pre = tmp;
    }
#pragma unroll
    for (int i = 0; i < 4; ++i)
#pragma unroll
        for (int j = 0; j < 4; ++j) {
            int row = bm + wr + i * 16 + quad * 4;
            int col = bn + wc + j * 16 + l16;
            float* p = C + (size_t)row * TN + col;
#pragma unroll
            for (int r = 0; r < 4; ++r) p[(size_t)r * TN] = acc[i][j][r];
        }
}

// ---------------- softmax of (S0+S1), single-pass (fp32 in, fp16 P out) ----------------
__global__ void softmax_add_kernel(const float* __restrict__ S0,
                                   const float* __restrict__ S1,
                                   f16* __restrict__ P) {
    __shared__ float red[256];
    const int row = blockIdx.x, tid = threadIdx.x;
    const size_t base = (size_t)row * TN + tid * 8;
    f32x4 a0 = *(const f32x4*)(S0 + base);
    f32x4 a1 = *(const f32x4*)(S0 + base + 4);
    f32x4 b0 = *(const f32x4*)(S1 + base);
    f32x4 b1 = *(const f32x4*)(S1 + base + 4);
    float vals[8];
#pragma unroll
    for (int e = 0; e < 4; ++e) { vals[e] = a0[e] + b0[e]; vals[4 + e] = a1[e] + b1[e]; }
    float m = vals[0];
#pragma unroll
    for (int e = 1; e < 8; ++e) m = fmaxf(m, vals[e]);
    red[tid] = m; __syncthreads();
    for (int st = 128; st > 0; st >>= 1) { if (tid < st) red[tid] = fmaxf(red[tid], red[tid + st]); __syncthreads(); }
    m = red[0]; __syncthreads();
    float sum = 0.f;
#pragma unroll
    for (int e = 0; e < 8; ++e) { vals[e] = expf(vals[e] - m); sum += vals[e]; }
    red[tid] = sum; __syncthreads();
    for (int st = 128; st > 0; st >>= 1) { if (tid < st) red[tid] += red[tid + st]; __syncthreads(); }
    float inv = 1.f / red[0];
    f16x8 o;
#pragma unroll
    for (int e = 0; e < 8; ++e) o[e] = (f16)(vals[e] * inv);
    *(f16x8*)(P + base) = o;
}

extern "C" void kernel_launch(void* const* d_in, const int* in_sizes, int n_in,
                              void* d_out, int out_size, void* d_ws, size_t ws_size,
                              hipStream_t stream) {
    const float* x = (const float*)d_in[0];
    const float* q = (const float*)d_in[1];
    const float* k = (const float*)d_in[2];
    const float* v = (const float*)d_in[3];
    float* out = (float*)d_out;
    const size_t M = (size_t)TN * TN;

    float* W1 = (float*)d_ws;
    float* W2 = W1 + M;
    f16* pl = (f16*)(W2 + M);
    f16 *x0 = pl,         *x1 = pl + M;
    f16 *q0 = pl + 2 * M, *q1 = pl + 3 * M;
    f16 *k0 = pl + 4 * M, *k1 = pl + 5 * M;
    f16 *v0 = pl + 6 * M;
    f16 *a0 = q0, *a1 = q1;   // xq split reuses q planes
    f16 *b0 = k0, *b1 = k1;   // xk split reuses k planes
    f16 *p0 = x1, *c0 = x0;   // P reuses x1, C reuses x0

    dim3 bs(256), bs3(512);
    dim3 gelem(TN * TN / 4 / 256);
    dim3 gt(TN / 64, TN / 64);
    dim3 gg3(TN / 256, TN / 128, 2);   // 256 blocks, 1/CU
    dim3 gg1(TN / 128, TN / 128, 2);   // 512 blocks, 2/CU

    hipLaunchKernelGGL(split2_kernel,  gelem, bs, 0, stream, x, x0, x1);
    hipLaunchKernelGGL(cast1t_kernel,  gt,    bs, 0, stream, v, v0);
    hipLaunchKernelGGL(split2t_kernel, gt,    bs, 0, stream, q, q0, q1);
    hipLaunchKernelGGL(gemm3_f16, gg3, bs3, 0, stream, x0, x1, q0, q1, W1, W2);
    hipLaunchKernelGGL(split2_add_kernel, gelem, bs, 0, stream, W1, W2, a0, a1);
    hipLaunchKernelGGL(split2t_kernel, gt, bs, 0, stream, k, k0, k1);
    hipLaunchKernelGGL(gemm3_f16, gg3, bs3, 0, stream, x0, x1, k0, k1, W1, W2);
    hipLaunchKernelGGL(split2t_add_kernel, gt, bs, 0, stream, W1, W2, b0, b1);
    hipLaunchKernelGGL(gemm3_f16, gg3, bs3, 0, stream, a0, a1, b0, b1, W1, W2);
    hipLaunchKernelGGL(softmax_add_kernel, dim3(TN), bs, 0, stream, W1, W2, p0);
    hipLaunchKernelGGL(gemm1_f16, gg1, bs, 0, stream, x0, v0, W1, W2);
    hipLaunchKernelGGL(cast1t_add_kernel, gt, bs, 0, stream, W1, W2, c0);
    hipLaunchKernelGGL(gemm1_f16, gg1, bs, 0, stream, p0, c0, W1, W2);
    hipLaunchKernelGGL(final_add_kernel, gelem, bs, 0, stream, W1, W2, out);
}

// Round 9
// 382.962 us; speedup vs baseline: 1.3562x; 1.0218x over previous
//
#include <hip/hip_runtime.h>
#include <stdint.h>

// softmax((x@q)@(x@k)) @ (x@v), N=2048, fp32 in/out.
// R14: bank R12's measured +19% per-CU efficiency (256^2 tile, 64x128 wave
// tiles) by giving it FULL machine fill: fuse gemm3#1+#2 into one dispatch
// computing x_split @ [q|k] (2048x4096 out) -> grid (16,8,2)=256 blocks=1/CU
// with the R12-verified body (only operand/output plumbing changed).
// xk partials: W3=d_out (dead until final dispatch) + W4 (+16.8MB ws).
// Runtime ws_size guard: if ws < 26*M bytes, fall back to the exact R10
// unfused sequence (known-good 390.8us config). gemm3#3 = R10 variant
// (best measured 62.4us). gemm1/elementwise/softmax unchanged.
// Numerics unchanged (absmax 1.0 across R8-R13): fp16 2-term split, unscaled
// residual, 3 products into one acc; K-split z=0/1 partials; consumers add.

#define TN 2048

typedef float f32x4 __attribute__((ext_vector_type(4)));
typedef _Float16 f16;
typedef f16 f16x8 __attribute__((ext_vector_type(8)));
typedef f16 f16x4 __attribute__((ext_vector_type(4)));

#define MFMA16(a, b, c) __builtin_amdgcn_mfma_f32_16x16x32_f16(a, b, c, 0, 0, 0)
#define SBAR() asm volatile("s_barrier" ::: "memory")
#define VMCNT(n) asm volatile("s_waitcnt vmcnt(" #n ")" ::: "memory")

// async global->LDS, 16B/lane. lds base wave-uniform; HW adds lane*16.
__device__ __forceinline__ void glds16(const f16* g, f16* l) {
    __builtin_amdgcn_global_load_lds(
        (const __attribute__((address_space(1))) unsigned int*)g,
        (__attribute__((address_space(3))) unsigned int*)l, 16, 0, 0);
}

// ---------------- split kernels: a ~= t0 + t1 (residual UNSCALED) ----------------
__global__ void split2_kernel(const float* __restrict__ in,
                              f16* __restrict__ t0, f16* __restrict__ t1) {
    int i = (blockIdx.x * 256 + threadIdx.x) * 4;
    f32x4 f = *(const f32x4*)(in + i);
    f16x4 o0, o1;
#pragma unroll
    for (int e = 0; e < 4; ++e) {
        float a = f[e];
        f16 h0 = (f16)a;
        o0[e] = h0; o1[e] = (f16)(a - (float)h0);
    }
    *(f16x4*)(t0 + i) = o0; *(f16x4*)(t1 + i) = o1;
}

__global__ void split2_add_kernel(const float* __restrict__ inA,
                                  const float* __restrict__ inB,
                                  f16* __restrict__ t0, f16* __restrict__ t1) {
    int i = (blockIdx.x * 256 + threadIdx.x) * 4;
    f32x4 fa = *(const f32x4*)(inA + i);
    f32x4 fb = *(const f32x4*)(inB + i);
    f16x4 o0, o1;
#pragma unroll
    for (int e = 0; e < 4; ++e) {
        float a = fa[e] + fb[e];
        f16 h0 = (f16)a;
        o0[e] = h0; o1[e] = (f16)(a - (float)h0);
    }
    *(f16x4*)(t0 + i) = o0; *(f16x4*)(t1 + i) = o1;
}

__global__ void split2t_kernel(const float* __restrict__ in,
                               f16* __restrict__ t0, f16* __restrict__ t1) {
    __shared__ f16 s0[64][68], s1[64][68];
    int bc = blockIdx.x * 64, br = blockIdx.y * 64;
    int tx = threadIdx.x & 15, ty = threadIdx.x >> 4;
#pragma unroll
    for (int rr = 0; rr < 64; rr += 16) {
        int r = rr + ty;
        f32x4 f = *(const f32x4*)(in + (size_t)(br + r) * TN + bc + tx * 4);
#pragma unroll
        for (int e = 0; e < 4; ++e) {
            float a = f[e];
            f16 h0 = (f16)a;
            s0[tx * 4 + e][r] = h0; s1[tx * 4 + e][r] = (f16)(a - (float)h0);
        }
    }
    __syncthreads();
#pragma unroll
    for (int rr = 0; rr < 64; rr += 16) {
        int c = rr + ty;
        f16x4 o0, o1;
#pragma unroll
        for (int e = 0; e < 4; ++e) { o0[e] = s0[c][tx*4+e]; o1[e] = s1[c][tx*4+e]; }
        size_t off = (size_t)(bc + c) * TN + br + tx * 4;
        *(f16x4*)(t0 + off) = o0; *(f16x4*)(t1 + off) = o1;
    }
}

__global__ void split2t_add_kernel(const float* __restrict__ inA,
                                   const float* __restrict__ inB,
                                   f16* __restrict__ t0, f16* __restrict__ t1) {
    __shared__ f16 s0[64][68], s1[64][68];
    int bc = blockIdx.x * 64, br = blockIdx.y * 64;
    int tx = threadIdx.x & 15, ty = threadIdx.x >> 4;
#pragma unroll
    for (int rr = 0; rr < 64; rr += 16) {
        int r = rr + ty;
        size_t off = (size_t)(br + r) * TN + bc + tx * 4;
        f32x4 fa = *(const f32x4*)(inA + off);
        f32x4 fb = *(const f32x4*)(inB + off);
#pragma unroll
        for (int e = 0; e < 4; ++e) {
            float a = fa[e] + fb[e];
            f16 h0 = (f16)a;
            s0[tx * 4 + e][r] = h0; s1[tx * 4 + e][r] = (f16)(a - (float)h0);
        }
    }
    __syncthreads();
#pragma unroll
    for (int rr = 0; rr < 64; rr += 16) {
        int c = rr + ty;
        f16x4 o0, o1;
#pragma unroll
        for (int e = 0; e < 4; ++e) { o0[e] = s0[c][tx*4+e]; o1[e] = s1[c][tx*4+e]; }
        size_t off = (size_t)(bc + c) * TN + br + tx * 4;
        *(f16x4*)(t0 + off) = o0; *(f16x4*)(t1 + off) = o1;
    }
}

__global__ void cast1t_kernel(const float* __restrict__ in, f16* __restrict__ t0) {
    __shared__ f16 s0[64][68];
    int bc = blockIdx.x * 64, br = blockIdx.y * 64;
    int tx = threadIdx.x & 15, ty = threadIdx.x >> 4;
#pragma unroll
    for (int rr = 0; rr < 64; rr += 16) {
        int r = rr + ty;
        f32x4 f = *(const f32x4*)(in + (size_t)(br + r) * TN + bc + tx * 4);
#pragma unroll
        for (int e = 0; e < 4; ++e) s0[tx * 4 + e][r] = (f16)f[e];
    }
    __syncthreads();
#pragma unroll
    for (int rr = 0; rr < 64; rr += 16) {
        int c = rr + ty;
        f16x4 o0;
#pragma unroll
        for (int e = 0; e < 4; ++e) o0[e] = s0[c][tx*4+e];
        *(f16x4*)(t0 + (size_t)(bc + c) * TN + br + tx * 4) = o0;
    }
}

__global__ void cast1t_add_kernel(const float* __restrict__ inA,
                                  const float* __restrict__ inB,
                                  f16* __restrict__ t0) {
    __shared__ f16 s0[64][68];
    int bc = blockIdx.x * 64, br = blockIdx.y * 64;
    int tx = threadIdx.x & 15, ty = threadIdx.x >> 4;
#pragma unroll
    for (int rr = 0; rr < 64; rr += 16) {
        int r = rr + ty;
        size_t off = (size_t)(br + r) * TN + bc + tx * 4;
        f32x4 fa = *(const f32x4*)(inA + off);
        f32x4 fb = *(const f32x4*)(inB + off);
#pragma unroll
        for (int e = 0; e < 4; ++e) s0[tx * 4 + e][r] = (f16)(fa[e] + fb[e]);
    }
    __syncthreads();
#pragma unroll
    for (int rr = 0; rr < 64; rr += 16) {
        int c = rr + ty;
        f16x4 o0;
#pragma unroll
        for (int e = 0; e < 4; ++e) o0[e] = s0[c][tx*4+e];
        *(f16x4*)(t0 + (size_t)(bc + c) * TN + br + tx * 4) = o0;
    }
}

__global__ void final_add_kernel(const float* __restrict__ inA,
                                 const float* __restrict__ inB,
                                 float* __restrict__ out) {
    int i = (blockIdx.x * 256 + threadIdx.x) * 4;
    f32x4 fa = *(const f32x4*)(inA + i);
    f32x4 fb = *(const f32x4*)(inB + i);
    f32x4 o;
#pragma unroll
    for (int e = 0; e < 4; ++e) o[e] = fa[e] + fb[e];
    *(f32x4*)(out + i) = o;
}

// ---------------- FUSED QK gemm: x_split @ [q|k], 256x256 tile, R12 body ----------------
// Grid (16,8,2): bx<8 -> q half, bx>=8 -> k half. z selects partial buffer.
// Segs: 0-15 a0, 16-31 a1, 32-47 b0, 48-63 b1 (b planes chosen by half).
__global__ __launch_bounds__(512, 2) void gemmqk_f16(
    const f16* __restrict__ a0p, const f16* __restrict__ a1p,
    const f16* __restrict__ q0p, const f16* __restrict__ q1p,
    const f16* __restrict__ k0p, const f16* __restrict__ k1p,
    float* __restrict__ Wq0, float* __restrict__ Wq1,
    float* __restrict__ Wk0, float* __restrict__ Wk1) {
    __shared__ f16 lds[2][64 * 512];  // 128 KB
    const int tid = threadIdx.x;
    const int wave = tid >> 6, lane = tid & 63;
    const int wrow = wave >> 1, wcol = wave & 1;   // 4x2 waves, 64x128 each
    const int quad = lane >> 4, l16 = lane & 15;
    const int bm = blockIdx.y * 256;
    const int bnf = blockIdx.x * 256;
    const int bsel = bnf >= TN;
    const int bc = bnf & (TN - 1);
    const int kbase = blockIdx.z * 1024;
    const f16* __restrict__ b0p = bsel ? k0p : q0p;
    const f16* __restrict__ b1p = bsel ? k1p : q1p;
    float* __restrict__ C = bsel ? (blockIdx.z ? Wk1 : Wk0)
                                 : (blockIdx.z ? Wq1 : Wq0);

    const int ws = wave * 8;
    const f16* sp[8];
#pragma unroll
    for (int t = 0; t < 8; ++t) {
        int s = ws + t;
        const f16* base; int gr;
        if (s < 16)      { base = a0p; gr = bm + s * 16 + l16; }
        else if (s < 32) { base = a1p; gr = bm + (s - 16) * 16 + l16; }
        else if (s < 48) { base = b0p; gr = bc + (s - 32) * 16 + l16; }
        else             { base = b1p; gr = bc + (s - 48) * 16 + l16; }
        sp[t] = base + (size_t)gr * TN + kbase + quad * 8;
    }
    const int rof = lane * 8;
    const int sa0 = wrow * 4,      sa1 = 16 + wrow * 4;
    const int sb0 = 32 + wcol * 8, sb1 = 48 + wcol * 8;

    f32x4 acc[4][8];
#pragma unroll
    for (int i = 0; i < 4; ++i)
#pragma unroll
        for (int j = 0; j < 8; ++j) acc[i][j] = (f32x4){0.f, 0.f, 0.f, 0.f};

    // prologue: step0 -> buf0
#pragma unroll
    for (int t = 0; t < 8; ++t) { glds16(sp[t], &lds[0][(ws + t) * 512]); sp[t] += 32; }
    f16* cur = &lds[0][0]; f16* nxt = &lds[1][0];
    VMCNT(0); SBAR();

    f16x8 a0f[4], a1f[4], b0f[8], b1f[8];
#pragma unroll
    for (int i = 0; i < 4; ++i) a0f[i] = *(const f16x8*)(cur + (sa0 + i) * 512 + rof);
#pragma unroll
    for (int j = 0; j < 8; ++j) b0f[j] = *(const f16x8*)(cur + (sb0 + j) * 512 + rof);

    for (int step = 0; step < 32; ++step) {
        // ---- P1 ----
#pragma unroll
        for (int i = 0; i < 4; ++i) a1f[i] = *(const f16x8*)(cur + (sa1 + i) * 512 + rof);
        if (step < 31) {
#pragma unroll
            for (int t = 0; t < 8; ++t) { glds16(sp[t], nxt + (ws + t) * 512); sp[t] += 32; }
        }
        SBAR();
        __builtin_amdgcn_s_setprio(1);
#pragma unroll
        for (int i = 0; i < 4; ++i)
#pragma unroll
            for (int j = 0; j < 8; ++j) acc[i][j] = MFMA16(a0f[i], b0f[j], acc[i][j]);
        __builtin_amdgcn_s_setprio(0);
        SBAR();
        // ---- P2 ----
#pragma unroll
        for (int j = 0; j < 8; ++j) b1f[j] = *(const f16x8*)(cur + (sb1 + j) * 512 + rof);
        SBAR();
        __builtin_amdgcn_s_setprio(1);
#pragma unroll
        for (int i = 0; i < 4; ++i)
#pragma unroll
            for (int j = 0; j < 8; ++j) acc[i][j] = MFMA16(a1f[i], b0f[j], acc[i][j]);
        __builtin_amdgcn_s_setprio(0);
        SBAR();
        // ---- P3 ----
        __builtin_amdgcn_s_setprio(1);
#pragma unroll
        for (int i = 0; i < 4; ++i)
#pragma unroll
            for (int j = 0; j < 8; ++j) acc[i][j] = MFMA16(a0f[i], b1f[j], acc[i][j]);
        __builtin_amdgcn_s_setprio(0);
        if (step < 31) {
            VMCNT(0);
            SBAR();
#pragma unroll
            for (int i = 0; i < 4; ++i) a0f[i] = *(const f16x8*)(nxt + (sa0 + i) * 512 + rof);
#pragma unroll
            for (int j = 0; j < 8; ++j) b0f[j] = *(const f16x8*)(nxt + (sb0 + j) * 512 + rof);
        }
        f16* tmp = cur; cur = nxt; nxt = tmp;
    }
#pragma unroll
    for (int i = 0; i < 4; ++i)
#pragma unroll
        for (int j = 0; j < 8; ++j) {
            int row = bm + wrow * 64 + i * 16 + quad * 4;
            int col = bc + wcol * 128 + j * 16 + l16;
            float* p = C + (size_t)row * TN + col;
#pragma unroll
            for (int r = 0; r < 4; ++r) p[(size_t)r * TN] = acc[i][j][r];
        }
}

// ---------------- 3-product split GEMM, 128x256, 8 waves, 3-buf (R10 best) ----------------
__global__ __launch_bounds__(512, 2) void gemm3_f16(
    const f16* __restrict__ a0p, const f16* __restrict__ a1p,
    const f16* __restrict__ b0p, const f16* __restrict__ b1p,
    float* __restrict__ C0, float* __restrict__ C1) {
    __shared__ f16 lds[3][48 * 512];  // 144 KB
    const int tid = threadIdx.x;
    const int wave = tid >> 6, lane = tid & 63;
    const int wrow = wave >> 2, wcol = wave & 3;
    const int quad = lane >> 4, l16 = lane & 15;
    const int bm = blockIdx.y * 128, bn = blockIdx.x * 256;
    const int kbase = blockIdx.z * 1024;
    float* __restrict__ C = blockIdx.z ? C1 : C0;

    const int ws = wave * 6;
    const f16* sp[6];
#pragma unroll
    for (int t = 0; t < 6; ++t) {
        int s = ws + t;
        const f16* base; int gr;
        if (s < 8)       { base = a0p; gr = bm + s * 16 + l16; }
        else if (s < 16) { base = a1p; gr = bm + (s - 8) * 16 + l16; }
        else if (s < 32) { base = b0p; gr = bn + (s - 16) * 16 + l16; }
        else             { base = b1p; gr = bn + (s - 32) * 16 + l16; }
        sp[t] = base + (size_t)gr * TN + kbase + quad * 8;
    }
    const int rof = lane * 8;
    const int sa0 = wrow * 4, sa1 = 8 + wrow * 4;
    const int sb0 = 16 + wcol * 4, sb1 = 32 + wcol * 4;

    f32x4 acc[4][4];
#pragma unroll
    for (int i = 0; i < 4; ++i)
#pragma unroll
        for (int j = 0; j < 4; ++j) acc[i][j] = (f32x4){0.f, 0.f, 0.f, 0.f};

#pragma unroll
    for (int t = 0; t < 6; ++t) { glds16(sp[t], &lds[0][(ws + t) * 512]); sp[t] += 32; }
#pragma unroll
    for (int t = 0; t < 6; ++t) { glds16(sp[t], &lds[1][(ws + t) * 512]); sp[t] += 32; }
    f16* cur = &lds[0][0]; f16* nxt = &lds[1][0]; f16* pre = &lds[2][0];
    VMCNT(6); SBAR();

    f16x8 a0f[4], a1f[4], b0f[4], b1f[4];
#pragma unroll
    for (int i = 0; i < 4; ++i) a0f[i] = *(const f16x8*)(cur + (sa0 + i) * 512 + rof);
#pragma unroll
    for (int j = 0; j < 4; ++j) b0f[j] = *(const f16x8*)(cur + (sb0 + j) * 512 + rof);

    for (int step = 0; step < 32; ++step) {
        // ---- phase A ----
#pragma unroll
        for (int j = 0; j < 4; ++j) b1f[j] = *(const f16x8*)(cur + (sb1 + j) * 512 + rof);
        if (step < 30) {
#pragma unroll
            for (int t = 0; t < 3; ++t) { glds16(sp[t], pre + (ws + t) * 512); sp[t] += 32; }
        }
        SBAR();
        __builtin_amdgcn_s_setprio(1);
#pragma unroll
        for (int i = 0; i < 4; ++i)
#pragma unroll
            for (int j = 0; j < 4; ++j) acc[i][j] = MFMA16(a0f[i], b0f[j], acc[i][j]);
        __builtin_amdgcn_s_setprio(0);
        SBAR();
        // ---- phase B ----
#pragma unroll
        for (int i = 0; i < 4; ++i) a1f[i] = *(const f16x8*)(cur + (sa1 + i) * 512 + rof);
        if (step < 30) {
#pragma unroll
            for (int t = 3; t < 6; ++t) { glds16(sp[t], pre + (ws + t) * 512); sp[t] += 32; }
        }
        SBAR();
        __builtin_amdgcn_s_setprio(1);
#pragma unroll
        for (int i = 0; i < 4; ++i)
#pragma unroll
            for (int j = 0; j < 4; ++j) acc[i][j] = MFMA16(a0f[i], b1f[j], acc[i][j]);
        __builtin_amdgcn_s_setprio(0);
        SBAR();
        // ---- phase C ----
        __builtin_amdgcn_s_setprio(1);
#pragma unroll
        for (int i = 0; i < 4; ++i)
#pragma unroll
            for (int j = 0; j < 4; ++j) acc[i][j] = MFMA16(a1f[i], b0f[j], acc[i][j]);
        __builtin_amdgcn_s_setprio(0);
        if (step < 31) {
            if (step < 30) { VMCNT(6); } else { VMCNT(0); }
            SBAR();
#pragma unroll
            for (int i = 0; i < 4; ++i) a0f[i] = *(const f16x8*)(nxt + (sa0 + i) * 512 + rof);
#pragma unroll
            for (int j = 0; j < 4; ++j) b0f[j] = *(const f16x8*)(nxt + (sb0 + j) * 512 + rof);
        }
        f16* tmp = cur; cur = nxt; nxt = pre; pre = tmp;
    }
#pragma unroll
    for (int i = 0; i < 4; ++i)
#pragma unroll
        for (int j = 0; j < 4; ++j) {
            int row = bm + wrow * 64 + i * 16 + quad * 4;
            int col = bn + wcol * 64 + j * 16 + l16;
            float* p = C + (size_t)row * TN + col;
#pragma unroll
            for (int r = 0; r < 4; ++r) p[(size_t)r * TN] = acc[i][j][r];
        }
}

// ---------------- single-product GEMM, 128x128, 4 waves, 3-buf (R8) ----------------
__global__ __launch_bounds__(256, 2) void gemm1_f16(
    const f16* __restrict__ A, const f16* __restrict__ Bt,
    float* __restrict__ C0, float* __restrict__ C1) {
    __shared__ f16 lds[3][16 * 512];  // 48 KB
    const int tid = threadIdx.x;
    const int wave = tid >> 6, lane = tid & 63;
    const int wr = (wave >> 1) * 64, wc = (wave & 1) * 64;
    const int quad = lane >> 4, l16 = lane & 15;
    const int bm = blockIdx.y * 128, bn = blockIdx.x * 128;
    const int kbase = blockIdx.z * 1024;
    float* __restrict__ C = blockIdx.z ? C1 : C0;

    const int ws = wave * 4;
    const f16* sp[4];
#pragma unroll
    for (int t = 0; t < 4; ++t) {
        int s = ws + t;
        const f16* base; int gr;
        if (s < 8) { base = A;  gr = bm + s * 16 + l16; }
        else       { base = Bt; gr = bn + (s - 8) * 16 + l16; }
        sp[t] = base + (size_t)gr * TN + kbase + quad * 8;
    }
    const int rof = lane * 8;
    const int sa = (wr >> 4), sb = 8 + (wc >> 4);

    f32x4 acc[4][4];
#pragma unroll
    for (int i = 0; i < 4; ++i)
#pragma unroll
        for (int j = 0; j < 4; ++j) acc[i][j] = (f32x4){0.f, 0.f, 0.f, 0.f};

#pragma unroll
    for (int t = 0; t < 4; ++t) { glds16(sp[t], &lds[0][(ws + t) * 512]); sp[t] += 32; }
#pragma unroll
    for (int t = 0; t < 4; ++t) { glds16(sp[t], &lds[1][(ws + t) * 512]); sp[t] += 32; }
    f16* cur = &lds[0][0]; f16* nxt = &lds[1][0]; f16* pre = &lds[2][0];
    VMCNT(4); SBAR();

    f16x8 af[4], bf[4];
#pragma unroll
    for (int i = 0; i < 4; ++i) af[i] = *(const f16x8*)(cur + (sa + i) * 512 + rof);
#pragma unroll
    for (int j = 0; j < 4; ++j) bf[j] = *(const f16x8*)(cur + (sb + j) * 512 + rof);

    for (int step = 0; step < 32; ++step) {
        if (step < 30) {
#pragma unroll
            for (int t = 0; t < 4; ++t) { glds16(sp[t], pre + (ws + t) * 512); sp[t] += 32; }
        }
        SBAR();
        __builtin_amdgcn_s_setprio(1);
#pragma unroll
        for (int i = 0; i < 4; ++i)
#pragma unroll
            for (int j = 0; j < 4; ++j) acc[i][j] = MFMA16(af[i], bf[j], acc[i][j]);
        __builtin_amdgcn_s_setprio(0);
        if (step < 31) {
            if (step < 30) { VMCNT(4); } else { VMCNT(0); }
            SBAR();
#pragma unroll
            for (int i = 0; i < 4; ++i) af[i] = *(const f16x8*)(nxt + (sa + i) * 512 + rof);
#pragma unroll
            for (int j = 0; j < 4; ++j) bf[j] = *(const f16x8*)(nxt + (sb + j) * 512 + rof);
        }
        f16* tmp = cur; cur = nxt; nxt = pre; pre = tmp;
    }
#pragma unroll
    for (int i = 0; i < 4; ++i)
#pragma unroll
        for (int j = 0; j < 4; ++j) {
            int row = bm + wr + i * 16 + quad * 4;
            int col = bn + wc + j * 16 + l16;
            float* p = C + (size_t)row * TN + col;
#pragma unroll
            for (int r = 0; r < 4; ++r) p[(size_t)r * TN] = acc[i][j][r];
        }
}

// ---------------- softmax of (S0+S1), single-pass (fp32 in, fp16 P out) ----------------
__global__ void softmax_add_kernel(const float* __restrict__ S0,
                                   const float* __restrict__ S1,
                                   f16* __restrict__ P) {
    __shared__ float red[256];
    const int row = blockIdx.x, tid = threadIdx.x;
    const size_t base = (size_t)row * TN + tid * 8;
    f32x4 a0 = *(const f32x4*)(S0 + base);
    f32x4 a1 = *(const f32x4*)(S0 + base + 4);
    f32x4 b0 = *(const f32x4*)(S1 + base);
    f32x4 b1 = *(const f32x4*)(S1 + base + 4);
    float vals[8];
#pragma unroll
    for (int e = 0; e < 4; ++e) { vals[e] = a0[e] + b0[e]; vals[4 + e] = a1[e] + b1[e]; }
    float m = vals[0];
#pragma unroll
    for (int e = 1; e < 8; ++e) m = fmaxf(m, vals[e]);
    red[tid] = m; __syncthreads();
    for (int st = 128; st > 0; st >>= 1) { if (tid < st) red[tid] = fmaxf(red[tid], red[tid + st]); __syncthreads(); }
    m = red[0]; __syncthreads();
    float sum = 0.f;
#pragma unroll
    for (int e = 0; e < 8; ++e) { vals[e] = expf(vals[e] - m); sum += vals[e]; }
    red[tid] = sum; __syncthreads();
    for (int st = 128; st > 0; st >>= 1) { if (tid < st) red[tid] += red[tid + st]; __syncthreads(); }
    float inv = 1.f / red[0];
    f16x8 o;
#pragma unroll
    for (int e = 0; e < 8; ++e) o[e] = (f16)(vals[e] * inv);
    *(f16x8*)(P + base) = o;
}

extern "C" void kernel_launch(void* const* d_in, const int* in_sizes, int n_in,
                              void* d_out, int out_size, void* d_ws, size_t ws_size,
                              hipStream_t stream) {
    const float* x = (const float*)d_in[0];
    const float* q = (const float*)d_in[1];
    const float* k = (const float*)d_in[2];
    const float* v = (const float*)d_in[3];
    float* out = (float*)d_out;
    const size_t M = (size_t)TN * TN;

    float* W1 = (float*)d_ws;
    float* W2 = W1 + M;
    f16* pl = (f16*)(W2 + M);
    f16 *x0 = pl,         *x1 = pl + M;
    f16 *q0 = pl + 2 * M, *q1 = pl + 3 * M;
    f16 *k0 = pl + 4 * M, *k1 = pl + 5 * M;
    f16 *v0 = pl + 6 * M;
    f16 *a0 = q0, *a1 = q1;   // xq split reuses q planes
    f16 *b0 = k0, *b1 = k1;   // xk split reuses k planes
    f16 *p0 = x1, *c0 = x0;   // P reuses x1, C reuses x0
    float* W4 = (float*)(pl + 7 * M);  // extra 16.8MB (fused path only)
    float* W3 = out;                   // d_out free until final dispatch

    dim3 bs(256), bs3(512);
    dim3 gelem(TN * TN / 4 / 256);
    dim3 gt(TN / 64, TN / 64);
    dim3 gg3(TN / 256, TN / 128, 2);    // 256 blocks, 1/CU
    dim3 ggqk(2 * TN / 256, TN / 256, 2); // (16,8,2) = 256 blocks, 1/CU
    dim3 gg1(TN / 128, TN / 128, 2);    // 512 blocks, 2/CU

    const size_t need = (size_t)(3 * 4 + 7 * 2) * M;  // W1,W2,W4 + 7 f16 planes

    hipLaunchKernelGGL(split2_kernel,  gelem, bs, 0, stream, x, x0, x1);
    hipLaunchKernelGGL(cast1t_kernel,  gt,    bs, 0, stream, v, v0);
    hipLaunchKernelGGL(split2t_kernel, gt,    bs, 0, stream, q, q0, q1);

    if (ws_size >= need) {
        // fused QK path: full-machine 256^2 tiles
        hipLaunchKernelGGL(split2t_kernel, gt, bs, 0, stream, k, k0, k1);
        hipLaunchKernelGGL(gemmqk_f16, ggqk, bs3, 0, stream,
                           x0, x1, q0, q1, k0, k1, W1, W2, W3, W4);
        hipLaunchKernelGGL(split2_add_kernel,  gelem, bs, 0, stream, W1, W2, a0, a1);
        hipLaunchKernelGGL(split2t_add_kernel, gt,    bs, 0, stream, W3, W4, b0, b1);
    } else {
        // fallback: R10 unfused sequence (known-good)
        hipLaunchKernelGGL(gemm3_f16, gg3, bs3, 0, stream, x0, x1, q0, q1, W1, W2);
        hipLaunchKernelGGL(split2_add_kernel, gelem, bs, 0, stream, W1, W2, a0, a1);
        hipLaunchKernelGGL(split2t_kernel, gt, bs, 0, stream, k, k0, k1);
        hipLaunchKernelGGL(gemm3_f16, gg3, bs3, 0, stream, x0, x1, k0, k1, W1, W2);
        hipLaunchKernelGGL(split2t_add_kernel, gt, bs, 0, stream, W1, W2, b0, b1);
    }
    hipLaunchKernelGGL(gemm3_f16, gg3, bs3, 0, stream, a0, a1, b0, b1, W1, W2);
    hipLaunchKernelGGL(softmax_add_kernel, dim3(TN), bs, 0, stream, W1, W2, p0);
    hipLaunchKernelGGL(gemm1_f16, gg1, bs, 0, stream, x0, v0, W1, W2);
    hipLaunchKernelGGL(cast1t_add_kernel, gt, bs, 0, stream, W1, W2, c0);
    hipLaunchKernelGGL(gemm1_f16, gg1, bs, 0, stream, p0, c0, W1, W2);
    hipLaunchKernelGGL(final_add_kernel, gelem, bs, 0, stream, W1, W2, out);
}